// Round 15
// baseline (34.641 us; speedup 1.0000x reference)
//
#include <hip/hip_runtime.h>
#include <hip/hip_bf16.h>

#define BATCH 8
#define SEQ   8192
#define DIM   512

typedef float f32x4 __attribute__((ext_vector_type(4)));

#define INV2PI   0.15915494309189535f
#define SQRT_DIM 22.62741699796952f
// -log2(10000)/256  (div[k] = 2^(C2*k) = exp(-2k*ln(10000)/512))
#define C2 (-0.05190512648261504f)

// Workspace: [0,256KB) seg ids (int32).
#define SEG_BYTES ((size_t)BATCH * SEQ * 4)

// ---------------------------------------------------------------------------
// seg_kernel — BYTE-IDENTICAL to R14 (register-resident, 2 barriers, ~2us).
// One block per batch row, 256 threads, 32 tokens/thread in registers.
//
// Reference scan (step i = 1..SEQ-1, carry nc starts 0):
//   c=t[i]; p=t[i-1];
//   if (36<=c<=41) nc=2;
//   is_note = c<12;
//   flag = is_note ? ((p>=12)||(nc>0)) : (p<12);
//   if (is_note) nc-=1;
//   seg = inclusive cumsum of flags (flag for token 0 = 0)
//
// nc chunk transform (reset,val): T(nc)=reset?val:nc+val; applied to nc=0
// the prefix value is just val. compose(earlier A, later B) =
//   B.reset ? B : {A.reset, A.val+B.val}.
// ---------------------------------------------------------------------------
#define SEG_TPB 256
#define SCHUNK  (SEQ / SEG_TPB)   // 32

__global__ __launch_bounds__(SEG_TPB)
void seg_kernel(const int* __restrict__ tok, int* __restrict__ seg) {
    __shared__ int s_r[4], s_v[4], s_c[4];

    const int tid  = (int)threadIdx.x;
    const int lane = tid & 63;
    const int wv   = tid >> 6;
    const int b    = (int)blockIdx.x;
    const int* t   = tok + (size_t)b * SEQ;
    int*      sg   = seg + (size_t)b * SEQ;

    const int start = tid * SCHUNK;

    int4 tt[8];
    #pragma unroll
    for (int m = 0; m < 8; ++m)
        tt[m] = *reinterpret_cast<const int4*>(t + start + m * 4);

    const int pentry = (start > 0) ? t[start - 1] : 0;

    int c[SCHUNK];
    #pragma unroll
    for (int m = 0; m < 8; ++m) {
        c[4 * m + 0] = tt[m].x;  c[4 * m + 1] = tt[m].y;
        c[4 * m + 2] = tt[m].z;  c[4 * m + 3] = tt[m].w;
    }

    // ---- pass 1: per-thread nc transform (reset,val) ---------------------
    int reset = 0, val = 0;
    #pragma unroll
    for (int i = 0; i < SCHUNK; ++i) {
        if (i == 0 && start == 0) continue;
        const int cc = c[i];
        if (cc >= 36 && cc <= 41) { reset = 1; val = 2; }
        if (cc < 12) val -= 1;
    }

    int ir = reset, iv = val;
    #pragma unroll
    for (int off = 1; off < 64; off <<= 1) {
        const int pv = __shfl_up(iv, off);
        const int pr = __shfl_up(ir, off);
        if (lane >= off && !ir) { iv += pv; ir = pr; }
    }
    int er = __shfl_up(ir, 1), ev = __shfl_up(iv, 1);
    if (lane == 0) { er = 0; ev = 0; }
    if (lane == 63) { s_r[wv] = ir; s_v[wv] = iv; }
    __syncthreads();
    int bv = 0;
    #pragma unroll
    for (int w = 0; w < 4; ++w) {
        if (w < wv) { if (s_r[w]) bv = s_v[w]; else bv += s_v[w]; }
    }
    const int nc_entry = er ? ev : (bv + ev);

    // ---- pass 2+3 fused: flags + local prefix in regs --------------------
    int nc = nc_entry, cum = 0;
    int pref[SCHUNK];
    int p = pentry;
    #pragma unroll
    for (int i = 0; i < SCHUNK; ++i) {
        const int cc = c[i];
        int f = 0;
        if (!(i == 0 && start == 0)) {
            if (cc >= 36 && cc <= 41) nc = 2;
            const bool is_note = (cc < 12);
            f = is_note ? (int)((p >= 12) || (nc > 0)) : (int)(p < 12);
            if (is_note) nc -= 1;
        }
        cum += f;
        pref[i] = cum;
        p = cc;
    }

    int it = cum;
    #pragma unroll
    for (int off = 1; off < 64; off <<= 1) {
        const int pv = __shfl_up(it, off);
        if (lane >= off) it += pv;
    }
    int et = __shfl_up(it, 1);
    if (lane == 0) et = 0;
    if (lane == 63) s_c[wv] = it;
    __syncthreads();
    int boff = 0;
    #pragma unroll
    for (int w = 0; w < 4; ++w) {
        if (w < wv) boff += s_c[w];
    }
    const int run = boff + et;

    #pragma unroll
    for (int m = 0; m < 8; ++m) {
        int4 o;
        o.x = run + pref[4 * m + 0];
        o.y = run + pref[4 * m + 1];
        o.z = run + pref[4 * m + 2];
        o.w = run + pref[4 * m + 3];
        *reinterpret_cast<int4*>(sg + start + m * 4) = o;
    }
}

// ---------------------------------------------------------------------------
// out_kernel: same per-wave memory pattern as R13/R14 (proven: dense dA/dB
// bursts, inline trig, wave-uniform scalar tok/seg, NT stores, XCD slab
// swizzle). SINGLE CHANGE: TPB 256 -> 1024 (16 waves/block), 16384 -> 4096
// blocks — 4x fewer dispatch events; mapping 1 wave = 1 row unchanged.
// 4096 = 8 XCDs x 512 blocks x 16 rows = each XCD still owns one batch.
// ---------------------------------------------------------------------------
#define OUT_TPB    1024
#define OUT_BLOCKS ((BATCH * SEQ) / (OUT_TPB / 64))   // 4096

__global__ __launch_bounds__(OUT_TPB)
void out_kernel(const int*   __restrict__ tok,
                const int*   __restrict__ seg,
                const float* __restrict__ emb,
                float*       __restrict__ out) {
    // bijective slab swizzle: 4096 = 8 * 512; each XCD owns one batch
    const int bid = (int)blockIdx.x;
    const int vb  = ((bid & 7) << 9) | (bid >> 3);

    const int lane = (int)threadIdx.x & 63;
    const int row  = __builtin_amdgcn_readfirstlane(
                        vb * (OUT_TPB / 64) + ((int)threadIdx.x >> 6));

    const int   token = tok[row];   // scalar load (uniform)
    const float segf  = (float)seg[row];

    const int dA = lane << 2;
    const int dB = dA + 256;

    const float* erow = emb + (size_t)token * DIM;
    const f32x4 eA = *reinterpret_cast<const f32x4*>(erow + dA);
    const f32x4 eB = *reinterpret_cast<const f32x4*>(erow + dB);

    float vA[4], vB[4];
    #pragma unroll
    for (int j = 0; j < 2; ++j) {
        const float kA = (float)((dA >> 1) + j);
        float rA = segf * __builtin_amdgcn_exp2f(C2 * kA) * INV2PI;
        rA -= floorf(rA);
        vA[2 * j]     = __builtin_amdgcn_sinf(rA);
        vA[2 * j + 1] = __builtin_amdgcn_cosf(rA);

        const float kB = (float)((dB >> 1) + j);
        float rB = segf * __builtin_amdgcn_exp2f(C2 * kB) * INV2PI;
        rB -= floorf(rB);
        vB[2 * j]     = __builtin_amdgcn_sinf(rB);
        vB[2 * j + 1] = __builtin_amdgcn_cosf(rB);
    }

    f32x4 oA, oB;
    oA.x = eA.x * SQRT_DIM + vA[0];  oA.y = eA.y * SQRT_DIM + vA[1];
    oA.z = eA.z * SQRT_DIM + vA[2];  oA.w = eA.w * SQRT_DIM + vA[3];
    oB.x = eB.x * SQRT_DIM + vB[0];  oB.y = eB.y * SQRT_DIM + vB[1];
    oB.z = eB.z * SQRT_DIM + vB[2];  oB.w = eB.w * SQRT_DIM + vB[3];

    float* orow = out + (size_t)row * DIM;
    __builtin_nontemporal_store(oA, reinterpret_cast<f32x4*>(orow + dA));
    __builtin_nontemporal_store(oB, reinterpret_cast<f32x4*>(orow + dB));
}

extern "C" void kernel_launch(void* const* d_in, const int* in_sizes, int n_in,
                              void* d_out, int out_size, void* d_ws, size_t ws_size,
                              hipStream_t stream) {
    const int*   tok = (const int*)d_in[0];     // (BATCH, SEQ) int32
    const float* emb = (const float*)d_in[1];   // (VOCAB, DIM) f32
    float*       out = (float*)d_out;           // (BATCH, SEQ, DIM) f32
    int*         seg = (int*)d_ws;              // 256 KB scratch

    seg_kernel<<<BATCH, SEG_TPB, 0, stream>>>(tok, seg);
    out_kernel<<<OUT_BLOCKS, OUT_TPB, 0, stream>>>(tok, seg, emb, out);
}